// Round 1
// baseline (76.851 us; speedup 1.0000x reference)
//
#include <hip/hip_runtime.h>
#include <float.h>

#define BB 4
#define NN 2048
#define SS 256
#define FF 7680   // C_FEAT * NA = 128*60
#define PP 24

// ws layout (floats): [0,96) invDenom (padded to 128), [128, 128+BB*SS*PP) A_T[b][s][p]

// ---------------- kernel 1: denom[b][p] = 1/max(sum_n |part_seg|, 1e-12) ----------------
__global__ __launch_bounds__(256) void k1_denom(const float* __restrict__ ps,
                                                float* __restrict__ invd) {
    int b = blockIdx.x;
    int tid = threadIdx.x;
    float acc[PP];
#pragma unroll
    for (int p = 0; p < PP; ++p) acc[p] = 0.f;
    const float* base = ps + (size_t)b * NN * PP;
    for (int n = tid; n < NN; n += 256) {
        const float4* row = (const float4*)(base + n * PP);
#pragma unroll
        for (int v = 0; v < 6; ++v) {
            float4 x = row[v];
            acc[v * 4 + 0] += fabsf(x.x);
            acc[v * 4 + 1] += fabsf(x.y);
            acc[v * 4 + 2] += fabsf(x.z);
            acc[v * 4 + 3] += fabsf(x.w);
        }
    }
#pragma unroll
    for (int p = 0; p < PP; ++p) {
#pragma unroll
        for (int m = 1; m < 64; m <<= 1) acc[p] += __shfl_xor(acc[p], m);
    }
    __shared__ float red[4][PP];
    int wid = tid >> 6, lane = tid & 63;
    if (lane == 0) {
#pragma unroll
        for (int p = 0; p < PP; ++p) red[wid][p] = acc[p];
    }
    __syncthreads();
    if (tid < PP) {
        float s = red[0][tid] + red[1][tid] + red[2][tid] + red[3][tid];
        invd[b * PP + tid] = 1.0f / fmaxf(s, 1e-12f);
    }
}

// branchless insert of (v, vi) into ascending triple (t0,t1,t2)/(j0,j1,j2), strict <
#define INSERT3(v, vi)                                                       \
    {                                                                        \
        bool c0 = (v) < t0, c1 = (v) < t1, c2 = (v) < t2;                    \
        float n2 = c1 ? t1 : (c2 ? (v) : t2);                                \
        int m2 = c1 ? j1 : (c2 ? (vi) : j2);                                 \
        float n1 = c0 ? t0 : (c1 ? (v) : t1);                                \
        int m1 = c0 ? j0 : (c1 ? (vi) : j1);                                 \
        t0 = c0 ? (v) : t0;                                                  \
        j0 = c0 ? (vi) : j0;                                                 \
        t1 = n1; j1 = m1; t2 = n2; j2 = m2;                                  \
    }

// ---------------- kernel 2: 3-NN + scatter into A_T ----------------
// grid: BB*16 blocks, 256 threads. Each block: 128 n's, 2 threads per n (s-halves).
__global__ __launch_bounds__(256) void k2_scatter(const float* __restrict__ xyz1,
                                                  const float* __restrict__ xyz2,
                                                  const float* __restrict__ ps,
                                                  float* __restrict__ aT) {
    int b = blockIdx.x >> 4;
    int chunk = blockIdx.x & 15;
    int tid = threadIdx.x;

    __shared__ float4 kv[SS];
    __shared__ float aloc[SS][PP];

    {   // stage sparse coords + |p|^2
        int s = tid;
        float x = xyz2[b * 3 * SS + s];
        float y = xyz2[b * 3 * SS + SS + s];
        float z = xyz2[b * 3 * SS + 2 * SS + s];
        kv[s] = make_float4(x, y, z, x * x + y * y + z * z);
    }
    for (int i = tid; i < SS * PP; i += 256) ((float*)aloc)[i] = 0.f;
    __syncthreads();

    int h = tid & 1;
    int n = chunk * 128 + (tid >> 1);
    const float* x1p = xyz1 + ((size_t)b * NN + n) * 3;
    float x = x1p[0], y = x1p[1], z = x1p[2];
    float x1sq = x * x + y * y + z * z;

    float t0 = FLT_MAX, t1 = FLT_MAX, t2 = FLT_MAX;
    int j0 = 0, j1 = 0, j2 = 0;
    int sbeg = h * 128;
    for (int s = sbeg; s < sbeg + 128; ++s) {
        float4 c = kv[s];
        float dt = x * c.x;
        dt = fmaf(y, c.y, dt);
        dt = fmaf(z, c.z, dt);
        float d = fmaf(-2.f, dt, x1sq + c.w);
        INSERT3(d, s);
    }

    // exchange triples with partner lane, rebuild (lo = s<128 half, hi = s>=128 half)
    float pd0 = __shfl_xor(t0, 1), pd1 = __shfl_xor(t1, 1), pd2 = __shfl_xor(t2, 1);
    int pi0 = __shfl_xor(j0, 1), pi1 = __shfl_xor(j1, 1), pi2 = __shfl_xor(j2, 1);
    float hi0 = h ? t0 : pd0, hi1 = h ? t1 : pd1, hi2 = h ? t2 : pd2;
    int hj0 = h ? j0 : pi0, hj1 = h ? j1 : pi1, hj2 = h ? j2 : pi2;
    {
        float a0 = h ? pd0 : t0, a1 = h ? pd1 : t1, a2 = h ? pd2 : t2;
        int b0 = h ? pi0 : j0, b1 = h ? pi1 : j1, b2 = h ? pi2 : j2;
        t0 = a0; t1 = a1; t2 = a2; j0 = b0; j1 = b1; j2 = b2;
    }
    INSERT3(hi0, hj0);
    INSERT3(hi1, hj1);
    INSERT3(hi2, hj2);

    float w0 = 1.f / (t0 + 1e-8f);
    float w1 = 1.f / (t1 + 1e-8f);
    float w2 = 1.f / (t2 + 1e-8f);
    float wsum = w0 + w1 + w2;
    w0 /= wsum; w1 /= wsum; w2 /= wsum;

    // scatter: this lane handles 12 of the 24 parts
    const float* prow = ps + ((size_t)b * NN + n) * PP + h * 12;
    float4 pa = *(const float4*)(prow);
    float4 pb = *(const float4*)(prow + 4);
    float4 pc = *(const float4*)(prow + 8);
    float pv[12] = {pa.x, pa.y, pa.z, pa.w, pb.x, pb.y, pb.z, pb.w,
                    pc.x, pc.y, pc.z, pc.w};
    int pbase = h * 12;
#pragma unroll
    for (int j = 0; j < 12; ++j) {
        float v = pv[j];
        atomicAdd(&aloc[j0][pbase + j], v * w0);
        atomicAdd(&aloc[j1][pbase + j], v * w1);
        atomicAdd(&aloc[j2][pbase + j], v * w2);
    }
    __syncthreads();

    {   // flush block accumulator to global
        int s = tid;
        float* dst = aT + ((size_t)b * SS + s) * PP;
#pragma unroll
        for (int p = 0; p < PP; ++p) unsafeAtomicAdd(&dst[p], aloc[s][p]);
    }
}

// ---------------- kernel 3: out[b,p,f] = invd[b,p] * sum_s A_T[b,s,p]*pts2[b,f,s] ----------------
// grid: BB*120 blocks, 256 threads (4 waves). Wave q handles s in [q*64,(q+1)*64), lane = f.
__global__ __launch_bounds__(256) void k3_contract(const float* __restrict__ pts2,
                                                   const float* __restrict__ aT,
                                                   const float* __restrict__ invd,
                                                   float* __restrict__ out) {
    int bb = blockIdx.x;
    int b = bb / 120;
    int fbase = (bb % 120) * 64;
    int tid = threadIdx.x;
    int q = __builtin_amdgcn_readfirstlane(tid >> 6);  // wave-uniform s-quarter
    int fl = tid & 63;
    int f = fbase + fl;

    const float* prow = pts2 + ((size_t)b * FF + f) * SS + q * 64;
    const float* arow = aT + ((size_t)b * SS + q * 64) * PP;  // uniform -> s_load

    float acc[PP];
#pragma unroll
    for (int p = 0; p < PP; ++p) acc[p] = 0.f;

    for (int i = 0; i < 64; i += 4) {
        float4 pv = *(const float4*)(prow + i);
#pragma unroll
        for (int j = 0; j < 4; ++j) {
            float pj = (j == 0) ? pv.x : (j == 1) ? pv.y : (j == 2) ? pv.z : pv.w;
#pragma unroll
            for (int p = 0; p < PP; ++p)
                acc[p] = fmaf(arow[(i + j) * PP + p], pj, acc[p]);
        }
    }

    __shared__ float part[4][64][25];  // pad 24->25 to break bank conflicts
#pragma unroll
    for (int p = 0; p < PP; ++p) part[q][fl][p] = acc[p];
    __syncthreads();

    int fl2 = tid & 63;
    int pg = tid >> 6;
#pragma unroll
    for (int j = 0; j < 6; ++j) {
        int p = pg * 6 + j;
        float v = part[0][fl2][p] + part[1][fl2][p] + part[2][fl2][p] + part[3][fl2][p];
        v *= invd[b * PP + p];
        out[((size_t)b * PP + p) * FF + fbase + fl2] = v;
    }
}

extern "C" void kernel_launch(void* const* d_in, const int* in_sizes, int n_in,
                              void* d_out, int out_size, void* d_ws, size_t ws_size,
                              hipStream_t stream) {
    const float* xyz1 = (const float*)d_in[0];
    const float* xyz2 = (const float*)d_in[1];
    const float* pts2 = (const float*)d_in[2];
    const float* ps   = (const float*)d_in[3];
    float* out = (float*)d_out;
    float* invd = (float*)d_ws;
    float* aT = (float*)d_ws + 128;

    hipMemsetAsync(d_ws, 0, (size_t)(128 + BB * SS * PP) * sizeof(float), stream);
    k1_denom<<<BB, 256, 0, stream>>>(ps, invd);
    k2_scatter<<<BB * 16, 256, 0, stream>>>(xyz1, xyz2, ps, aT);
    k3_contract<<<BB * 120, 256, 0, stream>>>(pts2, aT, invd, out);
}

// Round 2
// 42.151 us; speedup vs baseline: 1.8232x; 1.8232x over previous
//
#include <hip/hip_runtime.h>
#include <float.h>

#define BB 4
#define NN 2048
#define SS 256
#define FF 7680   // C_FEAT * NA = 128*60
#define PP 24

#define KVPAD(s) ((s) + ((s) >> 5))

// ws layout (floats): [0,128) invDenom, [128, 128+BB*SS*PP) A_T[b][s][p],
//                     [128+BB*SS*PP, ...) per-chunk partials

// ---------------- kernel 1: invd[b][p] = 1/max(sum_n |part_seg|, 1e-12) ----------------
__global__ __launch_bounds__(256) void k1_denom(const float* __restrict__ ps,
                                                float* __restrict__ invd) {
    int b = blockIdx.x;
    int tid = threadIdx.x;
    float acc[PP];
#pragma unroll
    for (int p = 0; p < PP; ++p) acc[p] = 0.f;
    const float* base = ps + (size_t)b * NN * PP;
    for (int n = tid; n < NN; n += 256) {
        const float4* row = (const float4*)(base + n * PP);
#pragma unroll
        for (int v = 0; v < 6; ++v) {
            float4 x = row[v];
            acc[v * 4 + 0] += fabsf(x.x);
            acc[v * 4 + 1] += fabsf(x.y);
            acc[v * 4 + 2] += fabsf(x.z);
            acc[v * 4 + 3] += fabsf(x.w);
        }
    }
#pragma unroll
    for (int p = 0; p < PP; ++p) {
#pragma unroll
        for (int m = 1; m < 64; m <<= 1) acc[p] += __shfl_xor(acc[p], m);
    }
    __shared__ float red[4][PP];
    int wid = tid >> 6, lane = tid & 63;
    if (lane == 0) {
#pragma unroll
        for (int p = 0; p < PP; ++p) red[wid][p] = acc[p];
    }
    __syncthreads();
    if (tid < PP) {
        float s = red[0][tid] + red[1][tid] + red[2][tid] + red[3][tid];
        invd[b * PP + tid] = 1.0f / fmaxf(s, 1e-12f);
    }
}

// branchless insert of (v, vi) into ascending triple, strict < (incumbent wins ties)
#define INSERT3(v, vi)                                                       \
    {                                                                        \
        bool c0 = (v) < t0, c1 = (v) < t1, c2 = (v) < t2;                    \
        float n2 = c1 ? t1 : (c2 ? (v) : t2);                                \
        int m2 = c1 ? j1 : (c2 ? (vi) : j2);                                 \
        float n1 = c0 ? t0 : (c1 ? (v) : t1);                                \
        int m1 = c0 ? j0 : (c1 ? (vi) : j1);                                 \
        t0 = c0 ? (v) : t0;                                                  \
        j0 = c0 ? (vi) : j0;                                                 \
        t1 = n1; j1 = m1; t2 = n2; j2 = m2;                                  \
    }

// merge partner's triple; lower-s-range thread's triple is the base (wins ties)
#define MERGE_ROUND(m)                                                       \
    {                                                                        \
        float q0 = __shfl_xor(t0, (m)), q1 = __shfl_xor(t1, (m)),            \
              q2 = __shfl_xor(t2, (m));                                      \
        int r0 = __shfl_xor(j0, (m)), r1 = __shfl_xor(j1, (m)),              \
            r2 = __shfl_xor(j2, (m));                                        \
        bool lw = ((h & (m)) == 0);                                          \
        float is0 = lw ? q0 : t0, is1 = lw ? q1 : t1, is2 = lw ? q2 : t2;    \
        int ij0 = lw ? r0 : j0, ij1 = lw ? r1 : j1, ij2 = lw ? r2 : j2;      \
        float bs0 = lw ? t0 : q0, bs1 = lw ? t1 : q1, bs2 = lw ? t2 : q2;    \
        int bj0 = lw ? j0 : r0, bj1 = lw ? j1 : r1, bj2 = lw ? j2 : r2;      \
        t0 = bs0; t1 = bs1; t2 = bs2; j0 = bj0; j1 = bj1; j2 = bj2;          \
        INSERT3(is0, ij0);                                                   \
        INSERT3(is1, ij1);                                                   \
        INSERT3(is2, ij2);                                                   \
    }

// ---------------- kernel 2: 3-NN + scatter into per-block partial A ----------------
// TPN threads per n; block covers NPB=256/TPN n's; each thread scans SS/TPN s's.
template <int TPN, bool ATOMIC_OUT>
__global__ __launch_bounds__(256) void k2_scatter(const float* __restrict__ xyz1,
                                                  const float* __restrict__ xyz2,
                                                  const float* __restrict__ ps,
                                                  float* __restrict__ dst) {
    constexpr int NPB = 256 / TPN;
    constexpr int CHUNKS = NN / NPB;
    constexpr int SPT = SS / TPN;
    constexpr int PPT = PP / TPN;
    int b = blockIdx.x / CHUNKS;
    int chunk = blockIdx.x % CHUNKS;
    int tid = threadIdx.x;

    __shared__ float4 kv[SS + (SS >> 5)];
    __shared__ float aloc[SS][PP];

    {   // stage sparse coords + |p|^2, bank-swizzled
        int s = tid;
        float x = xyz2[b * 3 * SS + s];
        float y = xyz2[b * 3 * SS + SS + s];
        float z = xyz2[b * 3 * SS + 2 * SS + s];
        kv[KVPAD(s)] = make_float4(x, y, z, x * x + y * y + z * z);
    }
    for (int i = tid; i < SS * PP; i += 256) ((float*)aloc)[i] = 0.f;
    __syncthreads();

    int h = tid % TPN;
    int n = chunk * NPB + tid / TPN;
    const float* x1p = xyz1 + ((size_t)b * NN + n) * 3;
    float x = x1p[0], y = x1p[1], z = x1p[2];
    float x1sq = x * x + y * y + z * z;

    float t0 = FLT_MAX, t1 = FLT_MAX, t2 = FLT_MAX;
    int j0 = 0, j1 = 0, j2 = 0;
    int sbeg = h * SPT;
#pragma unroll 4
    for (int s = sbeg; s < sbeg + SPT; ++s) {
        float4 c = kv[KVPAD(s)];
        float dt = x * c.x;
        dt = fmaf(y, c.y, dt);
        dt = fmaf(z, c.z, dt);
        float d = fmaf(-2.f, dt, x1sq + c.w);
        INSERT3(d, s);
    }
#pragma unroll
    for (int m = 1; m < TPN; m <<= 1) { MERGE_ROUND(m); }

    float w0 = 1.f / (t0 + 1e-8f);
    float w1 = 1.f / (t1 + 1e-8f);
    float w2 = 1.f / (t2 + 1e-8f);
    float wsum = w0 + w1 + w2;
    w0 /= wsum; w1 /= wsum; w2 /= wsum;

    // scatter: this thread handles PPT of the 24 parts for its n
    const float* prow = ps + ((size_t)b * NN + n) * PP + h * PPT;
#pragma unroll
    for (int j = 0; j < PPT; ++j) {
        float v = prow[j];
        atomicAdd(&aloc[j0][h * PPT + j], v * w0);
        atomicAdd(&aloc[j1][h * PPT + j], v * w1);
        atomicAdd(&aloc[j2][h * PPT + j], v * w2);
    }
    __syncthreads();

    if (ATOMIC_OUT) {
        int s = tid;
        float* d2 = dst + ((size_t)b * SS + s) * PP;
#pragma unroll
        for (int p = 0; p < PP; ++p) unsafeAtomicAdd(&d2[p], aloc[s][p]);
    } else {
        float* d2 = dst + (size_t)blockIdx.x * (SS * PP);
        for (int i = tid; i < SS * PP; i += 256) d2[i] = ((float*)aloc)[i];
    }
}

// ---------------- kernel 2b: A_T[b][s][p] = sum_chunk partial[b][chunk][s][p] ----------------
template <int CHUNKS>
__global__ __launch_bounds__(256) void k2b_reduce(const float* __restrict__ partial,
                                                  float* __restrict__ aT) {
    int i = blockIdx.x * 256 + threadIdx.x;   // over BB*SS*PP
    int b = i / (SS * PP);
    int sp = i - b * (SS * PP);
    const float* src = partial + ((size_t)b * CHUNKS) * (SS * PP) + sp;
    float acc = 0.f;
#pragma unroll 4
    for (int c = 0; c < CHUNKS; ++c) acc += src[(size_t)c * (SS * PP)];
    aT[i] = acc;
}

// ---------------- kernel 3: out[b,p,f] = invd[b,p] * sum_s A_T[b,s,p]*pts2[b,f,s] ----------------
__global__ __launch_bounds__(256) void k3_contract(const float* __restrict__ pts2,
                                                   const float* __restrict__ aT,
                                                   const float* __restrict__ invd,
                                                   float* __restrict__ out) {
    int bb = blockIdx.x;
    int b = bb / 120;
    int fbase = (bb % 120) * 64;
    int tid = threadIdx.x;
    int q = __builtin_amdgcn_readfirstlane(tid >> 6);  // wave-uniform s-quarter
    int fl = tid & 63;
    int f = fbase + fl;

    const float* prow = pts2 + ((size_t)b * FF + f) * SS + q * 64;
    const float* arow = aT + ((size_t)b * SS + q * 64) * PP;  // uniform -> s_load

    float acc[PP];
#pragma unroll
    for (int p = 0; p < PP; ++p) acc[p] = 0.f;

    for (int i = 0; i < 64; i += 4) {
        float4 pv = *(const float4*)(prow + i);
#pragma unroll
        for (int j = 0; j < 4; ++j) {
            float pj = (j == 0) ? pv.x : (j == 1) ? pv.y : (j == 2) ? pv.z : pv.w;
#pragma unroll
            for (int p = 0; p < PP; ++p)
                acc[p] = fmaf(arow[(i + j) * PP + p], pj, acc[p]);
        }
    }

    __shared__ float part[4][64][25];  // pad 24->25 to break bank conflicts
#pragma unroll
    for (int p = 0; p < PP; ++p) part[q][fl][p] = acc[p];
    __syncthreads();

    int fl2 = tid & 63;
    int pg = tid >> 6;
#pragma unroll
    for (int j = 0; j < 6; ++j) {
        int p = pg * 6 + j;
        float v = part[0][fl2][p] + part[1][fl2][p] + part[2][fl2][p] + part[3][fl2][p];
        v *= invd[b * PP + p];
        out[((size_t)b * PP + p) * FF + fbase + fl2] = v;
    }
}

extern "C" void kernel_launch(void* const* d_in, const int* in_sizes, int n_in,
                              void* d_out, int out_size, void* d_ws, size_t ws_size,
                              hipStream_t stream) {
    const float* xyz1 = (const float*)d_in[0];
    const float* xyz2 = (const float*)d_in[1];
    const float* pts2 = (const float*)d_in[2];
    const float* ps   = (const float*)d_in[3];
    float* out = (float*)d_out;
    float* invd = (float*)d_ws;
    float* aT = (float*)d_ws + 128;
    float* partial = (float*)d_ws + 128 + BB * SS * PP;

    const size_t baseFloats = 128 + (size_t)BB * SS * PP;
    auto need = [&](int chunksTotal) {
        return (baseFloats + (size_t)chunksTotal * SS * PP) * sizeof(float);
    };

    k1_denom<<<BB, 256, 0, stream>>>(ps, invd);

    if (ws_size >= need(BB * 64)) {
        k2_scatter<8, false><<<BB * 64, 256, 0, stream>>>(xyz1, xyz2, ps, partial);
        k2b_reduce<64><<<(BB * SS * PP) / 256, 256, 0, stream>>>(partial, aT);
    } else if (ws_size >= need(BB * 32)) {
        k2_scatter<4, false><<<BB * 32, 256, 0, stream>>>(xyz1, xyz2, ps, partial);
        k2b_reduce<32><<<(BB * SS * PP) / 256, 256, 0, stream>>>(partial, aT);
    } else if (ws_size >= need(BB * 16)) {
        k2_scatter<2, false><<<BB * 16, 256, 0, stream>>>(xyz1, xyz2, ps, partial);
        k2b_reduce<16><<<(BB * SS * PP) / 256, 256, 0, stream>>>(partial, aT);
    } else {
        hipMemsetAsync(aT, 0, (size_t)BB * SS * PP * sizeof(float), stream);
        k2_scatter<2, true><<<BB * 16, 256, 0, stream>>>(xyz1, xyz2, ps, aT);
    }

    k3_contract<<<BB * 120, 256, 0, stream>>>(pts2, aT, invd, out);
}